// Round 5
// baseline (889.558 us; speedup 1.0000x reference)
//
#include <hip/hip_runtime.h>

#define N_NODES 100000
#define N_EDGES 1600000
#define D_IN 128
#define D_HID 64

#define BKT_SHIFT 8
#define BKT_NODES 256
#define NB ((N_NODES + BKT_NODES - 1) / BKT_NODES)   // 391 buckets
#define BKT_CAP 5376   // mean 4092, +20 sigma

typedef __attribute__((ext_vector_type(8))) short bf16x8;
typedef __attribute__((ext_vector_type(4))) float f32x4;

__device__ __forceinline__ unsigned short f2b(float f) {
    union { float f; unsigned u; } c; c.f = f;
    unsigned r = (c.u + 0x7FFFu + ((c.u >> 16) & 1u)) >> 16;   // RNE
    return (unsigned short)r;
}
__device__ __forceinline__ float blo(unsigned u) { return __uint_as_float(u << 16); }
__device__ __forceinline__ float bhi(unsigned u) { return __uint_as_float(u & 0xffff0000u); }

// ================= bucket cursor init =================
__global__ void k_initcur(int* __restrict__ cursor) {
    int t = blockIdx.x * blockDim.x + threadIdx.x;
    if (t < NB) cursor[t] = t * BKT_CAP;
}

// ================= partition edges into fixed-capacity bucket regions =================
// pairs[] entry packs (src << 8) | (dst & 255); bucket = dst >> 8. 4B per edge.
__global__ __launch_bounds__(256) void k_bscatter(const int* __restrict__ src,
                                                  const int* __restrict__ dst,
                                                  int* __restrict__ cursor,
                                                  int* __restrict__ pairs, int E) {
    __shared__ int hist[NB];
    __shared__ int lbase[NB];
    __shared__ int lcur[NB];
    int chunk = (E + gridDim.x - 1) / gridDim.x;
    int beg = blockIdx.x * chunk;
    int end = min(beg + chunk, E);
    int tid = threadIdx.x;
    for (int t = tid; t < NB; t += 256) hist[t] = 0;
    __syncthreads();
    for (int e = beg + tid; e < end; e += 256)
        atomicAdd(&hist[dst[e] >> BKT_SHIFT], 1);
    __syncthreads();
    for (int t = tid; t < NB; t += 256) {
        int h = hist[t];
        lbase[t] = h ? atomicAdd(&cursor[t], h) : 0;
        lcur[t] = 0;
    }
    __syncthreads();
    for (int e = beg + tid; e < end; e += 256) {
        int d = dst[e];
        int bk = d >> BKT_SHIFT;
        int pos = lbase[bk] + atomicAdd(&lcur[bk], 1);
        if (pos < (bk + 1) * BKT_CAP)
            pairs[pos] = (src[e] << BKT_SHIFT) | (d & (BKT_NODES - 1));
    }
}

// ================= per-bucket degree -> dis =================
__global__ __launch_bounds__(256) void k_deg(const int* __restrict__ pairs,
                                             const int* __restrict__ cursor,
                                             float* __restrict__ dis, int n) {
    __shared__ int cnt[BKT_NODES];
    int b = blockIdx.x, tid = threadIdx.x;
    int base = b * BKT_CAP;
    int eend = base + min(cursor[b] - base, BKT_CAP);
    cnt[tid] = 0;
    __syncthreads();
    for (int e = base + tid; e < eend; e += 256)
        atomicAdd(&cnt[pairs[e] & (BKT_NODES - 1)], 1);
    __syncthreads();
    int node = (b << BKT_SHIFT) + tid;
    if (node < n) dis[node] = rsqrtf((float)cnt[tid] + 1.0f);
}

// ================= layer 1 GEMM via bf16 MFMA =================
// Output layout interleaved for the gather: h1b[node*64 + 2*j]   = h[j]      (j<32)
//                                           h1b[node*64 + 2*j+1] = h[j+32]
// so one uint at h1u[node*32+j] = features (j, j+32).
#define LS 136
__global__ __launch_bounds__(256) void k_gemm1(const float* __restrict__ x,
                                               const float* __restrict__ W1,
                                               unsigned short* __restrict__ h1b, int n) {
    __shared__ unsigned short xs[64 * LS];
    __shared__ unsigned short ws[64 * LS];
    int tid = threadIdx.x;
    int node0 = blockIdx.x * 64;

    for (int i = 0; i < 32; ++i) {
        int e = tid + i * 256;
        int k = e >> 6, f = e & 63;
        ws[f * LS + k] = f2b(W1[e]);
    }
    for (int i = 0; i < 8; ++i) {
        int e4 = tid + i * 256;
        int node = e4 >> 5;
        int k = (e4 & 31) * 4;
        float4 v = make_float4(0.f, 0.f, 0.f, 0.f);
        if (node0 + node < n)
            v = ((const float4*)x)[((size_t)(node0 + node) * D_IN + k) >> 2];
        unsigned short* p = &xs[node * LS + k];
        p[0] = f2b(v.x); p[1] = f2b(v.y); p[2] = f2b(v.z); p[3] = f2b(v.w);
    }
    __syncthreads();

    int wv = tid >> 6;
    int lane = tid & 63;
    int m16 = lane & 15;
    int q = lane >> 4;

    bf16x8 afrag[4];
#pragma unroll
    for (int ks = 0; ks < 4; ++ks)
        afrag[ks] = *(const bf16x8*)&xs[(wv * 16 + m16) * LS + ks * 32 + q * 8];

    f32x4 acc[4];
#pragma unroll
    for (int ft = 0; ft < 4; ++ft) acc[ft] = (f32x4){0.f, 0.f, 0.f, 0.f};

#pragma unroll
    for (int ft = 0; ft < 4; ++ft)
#pragma unroll
        for (int ks = 0; ks < 4; ++ks) {
            bf16x8 bfrag = *(const bf16x8*)&ws[(ft * 16 + m16) * LS + ks * 32 + q * 8];
            acc[ft] = __builtin_amdgcn_mfma_f32_16x16x32_bf16(afrag[ks], bfrag, acc[ft], 0, 0, 0);
        }

#pragma unroll
    for (int ft = 0; ft < 4; ++ft) {
        int f = ft * 16 + m16;
        int pos = (f < 32) ? (2 * f) : (2 * (f - 32) + 1);
#pragma unroll
        for (int r = 0; r < 4; ++r) {
            int node = node0 + wv * 16 + q * 4 + r;
            if (node < n) h1b[(size_t)node * D_HID + pos] = f2b(acc[ft][r]);
        }
    }
}

// ================= edge-parallel agg1 + bias + ReLU + dot(W2) -> zd = z*dis =================
// One block per bucket. acc[256][64] fp32 in LDS (64KB), ds_add_f32 accumulation.
// Lane f2 owns features (f2, f2+32) -> one bank per lane per half-wave (conflict-free).
__global__ __launch_bounds__(512, 4) void k_bagg1(const int* __restrict__ pairs,
                                                  const int* __restrict__ cursor,
                                                  const float* __restrict__ dis,
                                                  const unsigned* __restrict__ h1u,
                                                  const float* __restrict__ b1,
                                                  const float* __restrict__ W2,
                                                  float* __restrict__ zd, int n) {
    __shared__ float acc[BKT_NODES * 64];   // 64 KB
    __shared__ float dis_l[BKT_NODES];
    int b = blockIdx.x, tid = threadIdx.x;
    int node0 = b << BKT_SHIFT;
    int base = b * BKT_CAP;
    int eend = base + min(cursor[b] - base, BKT_CAP);
    int wid = tid >> 6, lane = tid & 63, h = lane >> 5, f2 = lane & 31;

    if (tid < BKT_NODES) {
        int node = node0 + tid;
        dis_l[tid] = (node < n) ? dis[node] : 0.f;
    }
    __syncthreads();
    // self-loop init: acc[t][f2] = dd^2*h[f2], acc[t][f2+32] = dd^2*h[f2+32]
    for (int it = 0; it < 16; ++it) {
        int w = tid + it * 512;              // 0..8191
        int t = w >> 5, ff = w & 31;
        int node = node0 + t;
        float d = dis_l[t];
        float v0 = 0.f, v1 = 0.f;
        if (node < n) {
            unsigned u = h1u[(size_t)node * 32 + ff];
            v0 = d * d * blo(u);
            v1 = d * d * bhi(u);
        }
        acc[t * 64 + ff] = v0;
        acc[t * 64 + 32 + ff] = v1;
    }
    __syncthreads();

    // edge loop: each wave takes 64-edge batches; 2 edges per iteration (half-wave each)
    for (int jb = base + wid * 64; jb < eend; jb += 8 * 64) {
        int m = min(64, eend - jb);
        int pkv = 0; float wv = 0.f;
        if (lane < m) {
            pkv = pairs[jb + lane];
            wv = dis[pkv >> BKT_SHIFT] * dis_l[pkv & (BKT_NODES - 1)];
        }
#define EDGE2(p) { \
        int idx = (p) + h; \
        int pk = __shfl(pkv, idx); \
        float w = __shfl(wv, idx); \
        int s = pk >> BKT_SHIFT; \
        int dl = pk & (BKT_NODES - 1); \
        unsigned u = h1u[(size_t)s * 32 + f2]; \
        atomicAdd(&acc[dl * 64 + f2], w * blo(u)); \
        atomicAdd(&acc[dl * 64 + 32 + f2], w * bhi(u)); }
        if (m == 64) {
#pragma unroll 8
            for (int p = 0; p < 64; p += 2) EDGE2(p)
        } else {
            for (int p = 0; p < m; p += 2) EDGE2(p)   // idx==m tail has w==0 -> harmless
        }
#undef EDGE2
    }
    __syncthreads();

    // epilogue: z[i] = sum_f relu(acc+b1)*W2 ; zd = z*dis
    float b1f = b1[lane], w2f = W2[lane];
    for (int t = wid; t < BKT_NODES; t += 8) {
        int node = node0 + t;
        float v = fmaxf(acc[t * 64 + lane] + b1f, 0.f) * w2f;
#pragma unroll
        for (int off = 32; off > 0; off >>= 1) v += __shfl_xor(v, off);
        if (lane == 0 && node < n) zd[node] = v * dis_l[t];
    }
}

// ================= edge-parallel agg2 + fused padded output =================
__global__ __launch_bounds__(1024) void k_bagg2(const int* __restrict__ pairs,
                                                const int* __restrict__ cursor,
                                                const float* __restrict__ dis,
                                                const float* __restrict__ zd,
                                                const float* __restrict__ b2,
                                                float* __restrict__ out, int n) {
    __shared__ float yacc[BKT_NODES];
    __shared__ float dis_l[BKT_NODES];
    int b = blockIdx.x, tid = threadIdx.x;
    int node0 = b << BKT_SHIFT;
    int base = b * BKT_CAP;
    int eend = base + min(cursor[b] - base, BKT_CAP);
    if (tid < BKT_NODES) {
        int node = node0 + tid;
        yacc[tid] = (node < n) ? zd[node] : 0.f;    // self-loop
        dis_l[tid] = (node < n) ? dis[node] : 0.f;
    }
    __syncthreads();
    for (int e = base + tid; e < eend; e += 1024) {
        int pk = pairs[e];
        atomicAdd(&yacc[pk & (BKT_NODES - 1)], zd[pk >> BKT_SHIFT]);
    }
    __syncthreads();
    float bb = b2[0];
    for (int it = 0; it < 8; ++it) {
        int w = tid + it * 1024;                    // 0..8191 float4s
        int t = w >> 5, c = w & 31;
        int node = node0 + t;
        if (node < n) {
            float4 v = make_float4(0.f, 0.f, 0.f, 0.f);
            if (c == 0) v.x = yacc[t] * dis_l[t] + bb;
            ((float4*)out)[(size_t)node * 32 + c] = v;
        }
    }
}

extern "C" void kernel_launch(void* const* d_in, const int* in_sizes, int n_in,
                              void* d_out, int out_size, void* d_ws, size_t ws_size,
                              hipStream_t stream) {
    const float* x  = (const float*)d_in[0];
    const int*   ei = (const int*)d_in[1];   // [2, E] int32
    const float* W1 = (const float*)d_in[2];
    const float* b1 = (const float*)d_in[3];
    const float* W2 = (const float*)d_in[4];
    const float* b2 = (const float*)d_in[5];
    float* out = (float*)d_out;

    const int n = N_NODES;
    const int E = N_EDGES;
    const int* src = ei;
    const int* dst = ei + E;

    // ws: pairs int[NB*CAP] (8.4MB) | cursor[512] | dis[n] | h1b ushort[64n] | zd[n]
    int* pairs  = (int*)d_ws;
    int* cursor = pairs + (size_t)NB * BKT_CAP;
    float* dis  = (float*)(cursor + 512);
    unsigned short* h1b = (unsigned short*)(dis + n);
    float* zd   = (float*)(h1b + (size_t)n * D_HID);

    k_initcur<<<(NB + 255) / 256, 256, 0, stream>>>(cursor);
    k_bscatter<<<256, 256, 0, stream>>>(src, dst, cursor, pairs, E);
    k_deg<<<NB, 256, 0, stream>>>(pairs, cursor, dis, n);

    k_gemm1<<<(n + 63) / 64, 256, 0, stream>>>(x, W1, h1b, n);

    k_bagg1<<<NB, 512, 0, stream>>>(pairs, cursor, dis, (const unsigned*)h1b, b1, W2, zd, n);
    k_bagg2<<<NB, 1024, 0, stream>>>(pairs, cursor, dis, zd, b2, out, n);
}

// Round 6
// 238.674 us; speedup vs baseline: 3.7271x; 3.7271x over previous
//
#include <hip/hip_runtime.h>

#define N_NODES 100000
#define N_EDGES 1600000
#define D_IN 128
#define D_HID 64

#define BKT_SHIFT 9
#define BKT_NODES 512
#define NB ((N_NODES + BKT_NODES - 1) / BKT_NODES)   // 196 buckets
#define BKT_CAP 10240      // mean 8163, guard

typedef __attribute__((ext_vector_type(8))) short bf16x8;
typedef __attribute__((ext_vector_type(4))) float f32x4;

__device__ __forceinline__ unsigned short f2b(float f) {
    union { float f; unsigned u; } c; c.f = f;
    unsigned r = (c.u + 0x7FFFu + ((c.u >> 16) & 1u)) >> 16;   // RNE
    return (unsigned short)r;
}
__device__ __forceinline__ float blo(unsigned u) { return __uint_as_float(u << 16); }
__device__ __forceinline__ float bhi(unsigned u) { return __uint_as_float(u & 0xffff0000u); }

// ================= bucket cursor init =================
__global__ void k_initcur(int* __restrict__ cursor) {
    int t = blockIdx.x * blockDim.x + threadIdx.x;
    if (t < NB) cursor[t] = t * BKT_CAP;
}

// ================= partition edges into fixed-capacity bucket regions =================
// packed code: (src << 9) | (dst & 511); bucket = dst >> 9. 4B per edge.
__global__ __launch_bounds__(256) void k_bscatter(const int* __restrict__ src,
                                                  const int* __restrict__ dst,
                                                  int* __restrict__ cursor,
                                                  int* __restrict__ pairs, int E) {
    __shared__ int hist[NB];
    __shared__ int lbase[NB];
    __shared__ int lcur[NB];
    int chunk = (E + gridDim.x - 1) / gridDim.x;
    int beg = blockIdx.x * chunk;
    int end = min(beg + chunk, E);
    int tid = threadIdx.x;
    if (tid < NB) hist[tid] = 0;
    __syncthreads();
    for (int e = beg + tid; e < end; e += 256)
        atomicAdd(&hist[dst[e] >> BKT_SHIFT], 1);
    __syncthreads();
    if (tid < NB) {
        int h = hist[tid];
        lbase[tid] = h ? atomicAdd(&cursor[tid], h) : 0;
        lcur[tid] = 0;
    }
    __syncthreads();
    for (int e = beg + tid; e < end; e += 256) {
        int d = dst[e];
        int bk = d >> BKT_SHIFT;
        int pos = lbase[bk] + atomicAdd(&lcur[bk], 1);
        if (pos < (bk + 1) * BKT_CAP)
            pairs[pos] = (src[e] << BKT_SHIFT) | (d & (BKT_NODES - 1));
    }
}

// ================= per-bucket counting sort -> CSR (padded) =================
__global__ __launch_bounds__(256) void k_bsort(const int* __restrict__ pairs,
                                               const int* __restrict__ cursor,
                                               int* __restrict__ srcs_sorted,
                                               int* __restrict__ row_start,
                                               int* __restrict__ row_end,
                                               float* __restrict__ dis, int n) {
    __shared__ int cnt[BKT_NODES];
    __shared__ int exc[BKT_NODES];
    __shared__ int sorted[BKT_CAP];
    int b = blockIdx.x;
    int base = b * BKT_CAP;
    int nE = min(cursor[b] - base, BKT_CAP);
    int node0 = b << BKT_SHIFT;
    int tid = threadIdx.x;

    cnt[tid] = 0; cnt[tid + 256] = 0;
    __syncthreads();
    for (int k = tid; k < nE; k += 256)
        atomicAdd(&cnt[pairs[base + k] & (BKT_NODES - 1)], 1);
    __syncthreads();

    if (tid < 64) {   // wave-0 exclusive scan of cnt[512]
        int lane = tid;
        int run = 0;
        for (int c = 0; c < BKT_NODES; c += 64) {
            int v = cnt[c + lane];
            int inc = v;
            for (int off = 1; off < 64; off <<= 1) {
                int t = __shfl_up(inc, off);
                if (lane >= off) inc += t;
            }
            exc[c + lane] = run + inc - v;
            run += __shfl(inc, 63);
        }
    }
    __syncthreads();

    for (int t = tid; t < BKT_NODES; t += 256) {
        int node = node0 + t;
        if (node < n) {
            int rs = base + exc[t];
            row_start[node] = rs;
            row_end[node] = rs + cnt[t];
            dis[node] = rsqrtf((float)cnt[t] + 1.0f);
        }
    }
    __syncthreads();
    cnt[tid] = exc[tid]; cnt[tid + 256] = exc[tid + 256];
    __syncthreads();

    for (int k = tid; k < nE; k += 256) {
        int pk = pairs[base + k];
        int pos = atomicAdd(&cnt[pk & (BKT_NODES - 1)], 1);
        sorted[pos] = pk >> BKT_SHIFT;       // src id
    }
    __syncthreads();
    for (int k = tid; k < nE; k += 256)
        srcs_sorted[base + k] = sorted[k];
}

// ================= layer 1 GEMM via bf16 MFMA: h1b[node][f] (plain layout) =================
#define LS 136
__global__ __launch_bounds__(256) void k_gemm1(const float* __restrict__ x,
                                               const float* __restrict__ W1,
                                               unsigned short* __restrict__ h1b, int n) {
    __shared__ unsigned short xs[64 * LS];
    __shared__ unsigned short ws[64 * LS];
    int tid = threadIdx.x;
    int node0 = blockIdx.x * 64;

    for (int i = 0; i < 32; ++i) {
        int e = tid + i * 256;
        int k = e >> 6, f = e & 63;
        ws[f * LS + k] = f2b(W1[e]);
    }
    for (int i = 0; i < 8; ++i) {
        int e4 = tid + i * 256;
        int node = e4 >> 5;
        int k = (e4 & 31) * 4;
        float4 v = make_float4(0.f, 0.f, 0.f, 0.f);
        if (node0 + node < n)
            v = ((const float4*)x)[((size_t)(node0 + node) * D_IN + k) >> 2];
        unsigned short* p = &xs[node * LS + k];
        p[0] = f2b(v.x); p[1] = f2b(v.y); p[2] = f2b(v.z); p[3] = f2b(v.w);
    }
    __syncthreads();

    int wv = tid >> 6;
    int lane = tid & 63;
    int m16 = lane & 15;
    int q = lane >> 4;

    bf16x8 afrag[4];
#pragma unroll
    for (int ks = 0; ks < 4; ++ks)
        afrag[ks] = *(const bf16x8*)&xs[(wv * 16 + m16) * LS + ks * 32 + q * 8];

    f32x4 acc[4];
#pragma unroll
    for (int ft = 0; ft < 4; ++ft) acc[ft] = (f32x4){0.f, 0.f, 0.f, 0.f};

#pragma unroll
    for (int ft = 0; ft < 4; ++ft)
#pragma unroll
        for (int ks = 0; ks < 4; ++ks) {
            bf16x8 bfrag = *(const bf16x8*)&ws[(ft * 16 + m16) * LS + ks * 32 + q * 8];
            acc[ft] = __builtin_amdgcn_mfma_f32_16x16x32_bf16(afrag[ks], bfrag, acc[ft], 0, 0, 0);
        }

#pragma unroll
    for (int ft = 0; ft < 4; ++ft)
#pragma unroll
        for (int r = 0; r < 4; ++r) {
            int node = node0 + wv * 16 + q * 4 + r;
            if (node < n) h1b[(size_t)node * D_HID + ft * 16 + m16] = f2b(acc[ft][r]);
        }
}

// ================= fused agg1 + bias + ReLU + dot(W2) -> zd = z*dis =================
// One wave per dst node. 8 lanes per edge (uint4 = 8 bf16 feats/lane), 8 edges per
// iteration -> one 1KB VMEM instruction per 8 edges.
__global__ __launch_bounds__(256) void k_gather1(const int* __restrict__ srcs,
                                                 const int* __restrict__ row_start,
                                                 const int* __restrict__ row_end,
                                                 const float* __restrict__ dis,
                                                 const uint4* __restrict__ h4,
                                                 const float* __restrict__ b1,
                                                 const float* __restrict__ W2,
                                                 float* __restrict__ zd, int n) {
    int i = blockIdx.x * 4 + (threadIdx.x >> 6);
    if (i >= n) return;
    int lane = threadIdx.x & 63;
    int g = lane >> 3;        // edge slot within iteration
    int m8 = lane & 7;        // feature block (feats 8*m8 .. 8*m8+7)
    float dd = dis[i];

    float a0 = 0.f, a1 = 0.f, a2 = 0.f, a3 = 0.f, a4 = 0.f, a5 = 0.f, a6 = 0.f, a7 = 0.f;
    if (g == 0) {             // self-loop once
        uint4 u = h4[(size_t)i * 8 + m8];
        float w = dd * dd;
        a0 = w * blo(u.x); a1 = w * bhi(u.x);
        a2 = w * blo(u.y); a3 = w * bhi(u.y);
        a4 = w * blo(u.z); a5 = w * bhi(u.z);
        a6 = w * blo(u.w); a7 = w * bhi(u.w);
    }

    int beg = row_start[i], end = row_end[i];
    for (int jb = beg; jb < end; jb += 64) {
        int m = min(64, end - jb);
        int sv = 0; float wv = 0.f;
        if (lane < m) {
            sv = srcs[jb + lane];
            wv = dis[sv] * dd;
        }
        int pmax = (m + 7) >> 3;
#pragma unroll 4
        for (int p = 0; p < pmax; ++p) {
            int idx = p * 8 + g;
            int s = __shfl(sv, idx);
            float w = __shfl(wv, idx);      // 0 for padded slots -> harmless
            uint4 u = h4[(size_t)s * 8 + m8];
            a0 = fmaf(w, blo(u.x), a0); a1 = fmaf(w, bhi(u.x), a1);
            a2 = fmaf(w, blo(u.y), a2); a3 = fmaf(w, bhi(u.y), a3);
            a4 = fmaf(w, blo(u.z), a4); a5 = fmaf(w, bhi(u.z), a5);
            a6 = fmaf(w, blo(u.w), a6); a7 = fmaf(w, bhi(u.w), a7);
        }
    }

    // reduce across the 8 edge-groups (bits 3..5 of lane)
#pragma unroll
    for (int off = 8; off < 64; off <<= 1) {
        a0 += __shfl_xor(a0, off); a1 += __shfl_xor(a1, off);
        a2 += __shfl_xor(a2, off); a3 += __shfl_xor(a3, off);
        a4 += __shfl_xor(a4, off); a5 += __shfl_xor(a5, off);
        a6 += __shfl_xor(a6, off); a7 += __shfl_xor(a7, off);
    }
    // per-lane partial of z over its 8 feats
    float4 ba = ((const float4*)b1)[m8 * 2];
    float4 bb = ((const float4*)b1)[m8 * 2 + 1];
    float4 wa = ((const float4*)W2)[m8 * 2];
    float4 wb = ((const float4*)W2)[m8 * 2 + 1];
    float v = fmaxf(a0 + ba.x, 0.f) * wa.x + fmaxf(a1 + ba.y, 0.f) * wa.y
            + fmaxf(a2 + ba.z, 0.f) * wa.z + fmaxf(a3 + ba.w, 0.f) * wa.w
            + fmaxf(a4 + bb.x, 0.f) * wb.x + fmaxf(a5 + bb.y, 0.f) * wb.y
            + fmaxf(a6 + bb.z, 0.f) * wb.z + fmaxf(a7 + bb.w, 0.f) * wb.w;
#pragma unroll
    for (int off = 1; off < 8; off <<= 1) v += __shfl_xor(v, off);
    if (lane == 0) zd[i] = v * dd;
}

// ================= agg2 (lane-parallel) + fused padded output =================
__global__ __launch_bounds__(256) void k_gather2(const int* __restrict__ srcs,
                                                 const int* __restrict__ row_start,
                                                 const int* __restrict__ row_end,
                                                 const float* __restrict__ dis,
                                                 const float* __restrict__ zd,
                                                 const float* __restrict__ b2,
                                                 float* __restrict__ out, int n) {
    int i = blockIdx.x * 4 + (threadIdx.x >> 6);
    if (i >= n) return;
    int lane = threadIdx.x & 63;
    float acc = 0.f;
    int beg = row_start[i], end = row_end[i];
    for (int j = beg + lane; j < end; j += 64)
        acc += zd[srcs[j]];
#pragma unroll
    for (int off = 32; off > 0; off >>= 1) acc += __shfl_xor(acc, off);
    float y = (acc + zd[i]) * dis[i] + b2[0];
    float2 v = (lane == 0) ? make_float2(y, 0.f) : make_float2(0.f, 0.f);
    ((float2*)out)[(size_t)i * 64 + lane] = v;
}

extern "C" void kernel_launch(void* const* d_in, const int* in_sizes, int n_in,
                              void* d_out, int out_size, void* d_ws, size_t ws_size,
                              hipStream_t stream) {
    const float* x  = (const float*)d_in[0];
    const int*   ei = (const int*)d_in[1];   // [2, E] int32
    const float* W1 = (const float*)d_in[2];
    const float* b1 = (const float*)d_in[3];
    const float* W2 = (const float*)d_in[4];
    const float* b2 = (const float*)d_in[5];
    float* out = (float*)d_out;

    const int n = N_NODES;
    const int E = N_EDGES;
    const int* src = ei;
    const int* dst = ei + E;

    // ws: pairs int[NB*CAP] | srcs_sorted int[NB*CAP] | row_start[n] | row_end[n]
    //     | cursor[256] | dis[n] | h1b ushort[64n] | zd[n]    (~30 MB)
    int* pairs       = (int*)d_ws;
    int* srcs_sorted = pairs + (size_t)NB * BKT_CAP;
    int* row_start   = srcs_sorted + (size_t)NB * BKT_CAP;
    int* row_end     = row_start + n;
    int* cursor      = row_end + n;
    float* dis       = (float*)(cursor + 256);
    unsigned short* h1b = (unsigned short*)(dis + n);
    float* zd        = (float*)(h1b + (size_t)n * D_HID);

    k_initcur<<<1, 256, 0, stream>>>(cursor);
    k_bscatter<<<784, 256, 0, stream>>>(src, dst, cursor, pairs, E);
    k_bsort<<<NB, 256, 0, stream>>>(pairs, cursor, srcs_sorted, row_start, row_end, dis, n);

    k_gemm1<<<(n + 63) / 64, 256, 0, stream>>>(x, W1, h1b, n);

    k_gather1<<<(n + 3) / 4, 256, 0, stream>>>(srcs_sorted, row_start, row_end, dis,
                                               (const uint4*)h1b, b1, W2, zd, n);
    k_gather2<<<(n + 3) / 4, 256, 0, stream>>>(srcs_sorted, row_start, row_end, dis,
                                               zd, b2, out, n);
}